// Round 10
// baseline (511.509 us; speedup 1.0000x reference)
//
#include <hip/hip_runtime.h>

typedef short bf16x8 __attribute__((ext_vector_type(8)));
typedef float f32x4 __attribute__((ext_vector_type(4)));

#define STREP 512
#define MB 1048576

__device__ __forceinline__ float leaky_f(float z) { return fmaxf(z, 0.2f * z); }
__device__ __forceinline__ unsigned short f2b(float f) {
    unsigned u = __float_as_uint(f);
    return (unsigned short)((u + 0x7fffu + ((u >> 16) & 1u)) >> 16);  // RTNE
}
__device__ __forceinline__ float b2f(unsigned short h) {
    return __uint_as_float(((unsigned)h) << 16);
}
// Async DMA: each lane's 16 B -> LDS at (wave-uniform l) + lane*16. [m97/m104]
__device__ __forceinline__ void async16(const void* g, void* l) {
    __builtin_amdgcn_global_load_lds(
        (const __attribute__((address_space(1))) unsigned int*)g,
        (__attribute__((address_space(3))) unsigned int*)l, 16, 0, 0);
}

// ---------------------------------------------------------------------------
// x fp32 [V][4ci][4b] -> bf16 [V][4b][4ci]
// ---------------------------------------------------------------------------
__global__ __launch_bounds__(256) void cast_x(const float* __restrict__ x,
                                              unsigned short* __restrict__ out, int total) {
    int idx = blockIdx.x * 256 + threadIdx.x;
    if (idx >= total) return;
    int v = idx >> 4, b = (idx >> 2) & 3, ci = idx & 3;
    out[idx] = f2b(x[(size_t)v * 16 + ci * 4 + b]);
}

// ---------------------------------------------------------------------------
// All 8 weight prepacks in ONE launch (B-fragment order, zero-padded chunks)
// ---------------------------------------------------------------------------
__global__ __launch_bounds__(256) void prepack_all(
    const float* __restrict__ w0, const float* __restrict__ w1,
    const float* __restrict__ w2, const float* __restrict__ w3,
    const float* __restrict__ w4, const float* __restrict__ w5,
    const float* __restrict__ w6, const float* __restrict__ w7,
    unsigned short* __restrict__ WP) {
    int gid = blockIdx.x * 256 + threadIdx.x;  // < 2514944
    const float* W;
    int base, KC, NT;
    if (gid < 3072)        { W = w0; base = 0;       KC = 76;   NT = 2; }
    else if (gid < 22528)  { W = w1; base = 3072;    KC = 608;  NT = 2; }
    else if (gid < 61440)  { W = w2; base = 22528;   KC = 608;  NT = 4; }
    else if (gid < 139264) { W = w3; base = 61440;   KC = 1216; NT = 4; }
    else if (gid < 303104) { W = w4; base = 139264;  KC = 1216; NT = 8; }
    else if (gid < 614400) { W = w5; base = 303104;  KC = 2432; NT = 8; }
    else if (gid < 1269760){ W = w6; base = 614400;  KC = 2432; NT = 16; }
    else                   { W = w7; base = 1269760; KC = 4864; NT = 16; }
    int idx = gid - base;
    int j = idx & 7, lane = (idx >> 3) & 63, q = idx >> 9;
    int nt = q % NT, chunk = q / NT;
    int kc = chunk * 32 + (lane >> 4) * 8 + j;
    int cout = nt * 16 + (lane & 15);
    float v = (kc < KC) ? W[(size_t)cout * KC + kc] : 0.f;
    WP[gid] = f2b(v);
}

// ---------------------------------------------------------------------------
// Pair-tile MFMA conv on finished bf16 [V][4][C]. M-tile = 8 vertices x 2
// batches (pair p = xcd>>2 pinned). Block = 4 waves = 4 tiles. K-loop stages
// up to 10 chunks of async global_load_lds gathers (VGPR-free, all in flight)
// then consumes from LDS -> ONE exposed gather latency per stage, not 10.
// FUSE: raw bf16 store + per-block partial stats. !FUSE: split-K atomicAdd.
// ---------------------------------------------------------------------------
template <int CIN, int COUT, int NG, int CPS, int SPLIT, bool FUSE>
__global__ __launch_bounds__(256, 4) void conv_mfma(
    const unsigned short* __restrict__ act, const int* __restrict__ neigh,
    const unsigned short* __restrict__ wp, void* __restrict__ yout,
    float* __restrict__ opart, int V, int perx) {
    constexpr int LOGC = (CIN == 32) ? 5 : (CIN == 64) ? 6 : (CIN == 128) ? 7 : 8;
    constexpr int NT = COUT / 16;
    constexpr int NGRP = NT / NG;
    constexpr int STB = (CPS < 10) ? CPS : 10;      // chunks per stage
    constexpr int NST = (CPS + STB - 1) / STB;
    __shared__ __align__(16) unsigned char stage[4][STB * 1024];
    __shared__ int shn[4 * 152];
    __shared__ float ss[FUSE ? 2 * COUT : 1];
    const int T8 = (V + 7) >> 3;
    const int ST = (T8 + 3) >> 2;
    const int L = ST * NGRP * SPLIT;
    const int xcd = blockIdx.x & 7;
    const int p = xcd >> 2;
    const int li = (xcd & 3) * perx + (blockIdx.x >> 3);
    const int tid = threadIdx.x;
    if (li >= L) {
        if constexpr (FUSE) {
            float* pb = opart + (size_t)blockIdx.x * (2 * COUT);
            for (int t = tid; t < 2 * COUT; t += 256) pb[t] = 0.f;
        }
        return;
    }
    const int sp = li % SPLIT;
    const int t1 = li / SPLIT;
    const int ng = t1 % NGRP;
    const int stile = t1 / NGRP;
    const int lane = tid & 63, wib = tid >> 6;
    const int v0 = (stile * 4 + wib) * 8;
    const int m = lane & 15, quad = lane >> 4;
    const int vi = m >> 1, bb = m & 1;
    int* sn = shn + wib * 152;
    {
        const int lim = V * 19 - 1;
        for (int t = lane; t < 152; t += 64) {
            int src = v0 * 19 + t;
            sn[t] = neigh[src < lim ? src : lim];
        }
    }
    if constexpr (FUSE) {
        for (int t = tid; t < 2 * COUT; t += 256) ss[t] = 0.f;
    }
    __syncthreads();

    const unsigned short* wl = wp + ((size_t)(ng * NG) * 64 + lane) * 8;
    const int c0 = sp * CPS;
    const int boff = p * 2 + bb;
    unsigned char* myst = stage[wib];

    f32x4 acc[NG];
#pragma unroll
    for (int t = 0; t < NG; ++t) acc[t] = (f32x4){0.f, 0.f, 0.f, 0.f};

    for (int s = 0; s < NST; ++s) {
        if (s) __syncthreads();   // drain prev stage's ds_reads before reuse
#pragma unroll
        for (int i = 0; i < STB; ++i) {
            const int chl = s * STB + i;
            if (chl < CPS) {
                const int ch = c0 + chl;
                int k_nb = (ch * 32) >> LOGC;
                k_nb = k_nb < 18 ? k_nb : 18;   // zero-padded chunk clamp
                const int ci = ((ch * 32) & (CIN - 1)) + quad * 8;
                const int n = sn[vi * 19 + k_nb];
                async16(act + ((size_t)n * 4 + boff) * CIN + ci, myst + i * 1024);
            }
        }
        __syncthreads();          // vmcnt(0) drain: all DMA landed in LDS
#pragma unroll
        for (int i = 0; i < STB; ++i) {
            const int chl = s * STB + i;
            if (chl < CPS) {
                bf16x8 a = *(const bf16x8*)(myst + i * 1024 + (size_t)lane * 16);
                const unsigned short* wc = wl + (size_t)(c0 + chl) * NT * 512;
#pragma unroll
                for (int t = 0; t < NG; ++t) {
                    bf16x8 bfv = *(const bf16x8*)(wc + (size_t)t * 512);
                    acc[t] = __builtin_amdgcn_mfma_f32_16x16x32_bf16(a, bfv, acc[t], 0, 0, 0);
                }
            }
        }
    }

    // C/D row = quad*4+r -> v = v0 + quad*2 + (r>>1), batch = p*2 + (r&1)
    if constexpr (FUSE) {
        unsigned short* y = (unsigned short*)yout;
        float sl[NG], ql[NG];
#pragma unroll
        for (int t = 0; t < NG; ++t) { sl[t] = 0.f; ql[t] = 0.f; }
#pragma unroll
        for (int r = 0; r < 4; ++r) {
            int v = v0 + quad * 2 + (r >> 1);
            if (v < V) {
                size_t row = ((size_t)v * 4 + p * 2 + (r & 1)) * COUT;
#pragma unroll
                for (int t = 0; t < NG; ++t) {
                    int cout = (ng * NG + t) * 16 + m;
                    float val = acc[t][r];
                    y[row + cout] = f2b(val);
                    sl[t] += val;
                    ql[t] = fmaf(val, val, ql[t]);
                }
            }
        }
#pragma unroll
        for (int t = 0; t < NG; ++t) {
            int cout = (ng * NG + t) * 16 + m;
            atomicAdd(&ss[cout], sl[t]);
            atomicAdd(&ss[COUT + cout], ql[t]);
        }
        __syncthreads();
        float* pb = opart + (size_t)blockIdx.x * (2 * COUT);
        for (int t = tid; t < 2 * COUT; t += 256) pb[t] = ss[t];
    } else {
        float* y = (float*)yout;
#pragma unroll
        for (int r = 0; r < 4; ++r) {
            int v = v0 + quad * 2 + (r >> 1);
            if (v < V) {
                size_t row = ((size_t)v * 4 + p * 2 + (r & 1)) * COUT;
#pragma unroll
                for (int t = 0; t < NG; ++t)
                    atomicAdd(&y[row + (ng * NG + t) * 16 + m], acc[t][r]);
            }
        }
    }
}

// ---------------------------------------------------------------------------
// conv1_1: CIN=4, quad-tile (4 vertices x 4 batches). Raw bf16 out + stats.
// Only 3 chunks -> plain grouped loads are fine here.
// ---------------------------------------------------------------------------
__global__ __launch_bounds__(256) void conv1_mfma(
    const unsigned short* __restrict__ act, const int* __restrict__ neigh,
    const unsigned short* __restrict__ wp, unsigned short* __restrict__ y,
    float* __restrict__ opart, int V) {
    __shared__ int shn[4 * 76];
    __shared__ float ss[64];
    const int tid = threadIdx.x;
    const int lane = tid & 63, wib = tid >> 6;
    const int v0 = (blockIdx.x * 4 + wib) * 4;
    const int m = lane & 15, quad = lane >> 4;
    int* sn = shn + wib * 76;
    {
        const int lim = V * 19 - 1;
        for (int t = lane; t < 76; t += 64) {
            int src = v0 * 19 + t;
            sn[t] = neigh[src < lim ? src : lim];
        }
    }
    for (int t = tid; t < 64; t += 256) ss[t] = 0.f;
    __syncthreads();

    const unsigned short* wl = wp + (size_t)lane * 8;
    const int b = m & 3, vq = m >> 2;

    f32x4 acc[2] = {(f32x4){0.f, 0.f, 0.f, 0.f}, (f32x4){0.f, 0.f, 0.f, 0.f}};
    union { unsigned u[4]; bf16x8 v; } w[3];
    bf16x8 bfr[3][2];
#pragma unroll
    for (int ch = 0; ch < 3; ++ch) {
        int k0 = (ch * 32 + quad * 8) >> 2;
        int k0c = k0 < 18 ? k0 : 18;
        int k1c = k0 + 1 < 18 ? k0 + 1 : 18;
        const unsigned* p0 = (const unsigned*)(act + ((size_t)sn[vq * 19 + k0c] * 4 + b) * 4);
        const unsigned* p1 = (const unsigned*)(act + ((size_t)sn[vq * 19 + k1c] * 4 + b) * 4);
        w[ch].u[0] = p0[0]; w[ch].u[1] = p0[1];
        w[ch].u[2] = p1[0]; w[ch].u[3] = p1[1];   // OOB k: weights zero-padded
#pragma unroll
        for (int t = 0; t < 2; ++t)
            bfr[ch][t] = *(const bf16x8*)(wl + (size_t)ch * 1024 + (size_t)t * 512);
    }
    __builtin_amdgcn_sched_barrier(0);
#pragma unroll
    for (int ch = 0; ch < 3; ++ch)
#pragma unroll
        for (int t = 0; t < 2; ++t)
            acc[t] = __builtin_amdgcn_mfma_f32_16x16x32_bf16(w[ch].v, bfr[ch][t], acc[t], 0, 0, 0);

    float sl[2] = {0.f, 0.f}, ql[2] = {0.f, 0.f};
    int v = v0 + quad;
    if (v < V) {
        size_t rb = (size_t)v * 4 * 32;
#pragma unroll
        for (int r = 0; r < 4; ++r) {
#pragma unroll
            for (int t = 0; t < 2; ++t) {
                float val = acc[t][r];
                y[rb + (size_t)r * 32 + t * 16 + m] = f2b(val);
                sl[t] += val;
                ql[t] = fmaf(val, val, ql[t]);
            }
        }
    }
#pragma unroll
    for (int t = 0; t < 2; ++t) {
        atomicAdd(&ss[t * 16 + m], sl[t]);
        atomicAdd(&ss[32 + t * 16 + m], ql[t]);
    }
    __syncthreads();
    float* pb = opart + (size_t)blockIdx.x * 64;
    for (int t = tid; t < 64; t += 256) pb[t] = ss[t];
}

// ---------------------------------------------------------------------------
// Sum per-block partials: grid.x = 2*C; st[c] = sum_b part[b][c]
// ---------------------------------------------------------------------------
__global__ __launch_bounds__(256) void reduce_stats(const float* __restrict__ part,
                                                    float* __restrict__ st, int nblk) {
    __shared__ float red[256];
    int c = blockIdx.x;
    int C2 = gridDim.x;
    float s = 0.f;
    for (int b = threadIdx.x; b < nblk; b += 256) s += part[(size_t)b * C2 + c];
    red[threadIdx.x] = s;
    __syncthreads();
    for (int off = 128; off > 0; off >>= 1) {
        if (threadIdx.x < off) red[threadIdx.x] += red[threadIdx.x + off];
        __syncthreads();
    }
    if (threadIdx.x == 0) st[c] = red[0];
}

// ---------------------------------------------------------------------------
// Per-channel sum/sumsq of fp32 y [rows][C] -> per-XCD replicated stats
// ---------------------------------------------------------------------------
template <int C>
__global__ __launch_bounds__(256) void stats_kernel(const float* __restrict__ y,
                                                    float* __restrict__ st, int rows) {
    constexpr int LOGC = (C == 128) ? 7 : 8;
    __shared__ float ss[2 * C];
    int tid = threadIdx.x;
    for (int i = tid; i < 2 * C; i += 256) ss[i] = 0.f;
    __syncthreads();
    int c = tid & (C - 1);
    const int rpb = 256 >> LOGC;
    float s = 0.f, q = 0.f;
    for (int r = blockIdx.x * rpb + (tid >> LOGC); r < rows; r += gridDim.x * rpb) {
        float v = y[(size_t)r * C + c];
        s += v;
        q = fmaf(v, v, q);
    }
    atomicAdd(&ss[c], s);
    atomicAdd(&ss[C + c], q);
    __syncthreads();
    float* orep = st + (blockIdx.x & 7) * STREP;
    for (int i = tid; i < 2 * C; i += 256) atomicAdd(&orep[i], ss[i]);
}

// ---------------------------------------------------------------------------
// bnleaky -> finished bf16. BIN: raw bf16 in (plain stats). !BIN: fp32 in
// (replicated stats).
// ---------------------------------------------------------------------------
template <int C, bool BIN>
__global__ __launch_bounds__(256) void finalize_kernel(
    const void* __restrict__ yin, const float* __restrict__ st,
    const float* __restrict__ g, const float* __restrict__ be, float invN,
    unsigned short* __restrict__ out, int total4) {
    __shared__ float la[C], lc[C];
    int tid = threadIdx.x;
    for (int c = tid; c < C; c += 256) {
        float s, q;
        if constexpr (BIN) {
            s = st[c]; q = st[C + c];
        } else {
            s = 0.f; q = 0.f;
#pragma unroll
            for (int k = 0; k < 8; ++k) { s += st[k * STREP + c]; q += st[k * STREP + C + c]; }
        }
        float mu = s * invN;
        float var = fmaf(q, invN, -mu * mu);
        float a = g[c] * rsqrtf(var + 1e-5f);
        la[c] = a;
        lc[c] = fmaf(-mu, a, be[c]);
    }
    __syncthreads();
    int idx = blockIdx.x * 256 + tid;
    if (idx >= total4) return;
    int c0 = (idx * 4) & (C - 1);
    float v0, v1, v2, v3;
    if constexpr (BIN) {
        uint2 d = ((const uint2*)yin)[idx];
        v0 = b2f((unsigned short)(d.x & 0xffff));
        v1 = b2f((unsigned short)(d.x >> 16));
        v2 = b2f((unsigned short)(d.y & 0xffff));
        v3 = b2f((unsigned short)(d.y >> 16));
    } else {
        float4 yv = ((const float4*)yin)[idx];
        v0 = yv.x; v1 = yv.y; v2 = yv.z; v3 = yv.w;
    }
    float o0 = leaky_f(fmaf(la[c0 + 0], v0, lc[c0 + 0]));
    float o1 = leaky_f(fmaf(la[c0 + 1], v1, lc[c0 + 1]));
    float o2 = leaky_f(fmaf(la[c0 + 2], v2, lc[c0 + 2]));
    float o3 = leaky_f(fmaf(la[c0 + 3], v3, lc[c0 + 3]));
    unsigned r0 = (unsigned)f2b(o0) | ((unsigned)f2b(o1) << 16);
    unsigned r1 = (unsigned)f2b(o2) | ((unsigned)f2b(o3) << 16);
    ((uint2*)out)[idx] = make_uint2(r0, r1);
}

// ---------------------------------------------------------------------------
// Mean-pool on [Vin][4][C] -> [VP][4][C]. BN: producer bnleaky at gather.
// ---------------------------------------------------------------------------
template <int C, bool BN>
__global__ __launch_bounds__(256) void pool_kernel(
    const unsigned short* __restrict__ in, const int* __restrict__ neigh,
    const float* __restrict__ pstats, const float* __restrict__ pg,
    const float* __restrict__ pe, float invN,
    unsigned short* __restrict__ out, int total) {
    constexpr int LC4 = (C == 32) ? 3 : (C == 64) ? 4 : 5;
    __shared__ float2 lac[BN ? C : 1];
    int tid = threadIdx.x;
    if constexpr (BN) {
        for (int c = tid; c < C; c += 256) {
            float s = pstats[c], q = pstats[C + c];
            float mu = s * invN;
            float var = fmaf(q, invN, -mu * mu);
            float a = pg[c] * rsqrtf(var + 1e-5f);
            lac[c] = make_float2(a, fmaf(-mu, a, pe[c]));
        }
        __syncthreads();
    }
    int idx = blockIdx.x * 256 + tid;
    if (idx >= total) return;
    int c4 = idx & ((C / 4) - 1);
    int b = (idx >> LC4) & 3;
    int vp = idx >> (LC4 + 2);
    float a0 = 0.f, a1 = 0.f, a2 = 0.f, a3 = 0.f;
    for (int k = 0; k < 19; ++k) {
        int n = neigh[vp * 19 + k];
        uint2 d = *(const uint2*)(in + ((size_t)n * 4 + b) * C + c4 * 4);
        float f0 = b2f((unsigned short)(d.x & 0xffff));
        float f1 = b2f((unsigned short)(d.x >> 16));
        float f2 = b2f((unsigned short)(d.y & 0xffff));
        float f3 = b2f((unsigned short)(d.y >> 16));
        if constexpr (BN) {
            float2 t0 = lac[c4 * 4 + 0], t1 = lac[c4 * 4 + 1];
            float2 t2 = lac[c4 * 4 + 2], t3 = lac[c4 * 4 + 3];
            f0 = leaky_f(fmaf(f0, t0.x, t0.y));
            f1 = leaky_f(fmaf(f1, t1.x, t1.y));
            f2 = leaky_f(fmaf(f2, t2.x, t2.y));
            f3 = leaky_f(fmaf(f3, t3.x, t3.y));
        }
        a0 += f0; a1 += f1; a2 += f2; a3 += f3;
    }
    const float r = 1.f / 19.f;
    unsigned r0 = (unsigned)f2b(a0 * r) | ((unsigned)f2b(a1 * r) << 16);
    unsigned r1 = (unsigned)f2b(a2 * r) | ((unsigned)f2b(a3 * r) << 16);
    ((uint2*)out)[idx] = make_uint2(r0, r1);
}

// ---------------------------------------------------------------------------
// FC over bnleaky(y4_2 fp32 [642][4][256], replicated stats)
// ---------------------------------------------------------------------------
__global__ __launch_bounds__(256) void fc_partial(
    const float* __restrict__ y, const float* __restrict__ wfc,
    const float* __restrict__ st, const float* __restrict__ g,
    const float* __restrict__ be, float invN, float* __restrict__ fcacc) {
    __shared__ float la[256], lc[256];
    __shared__ float sh[4];
    int tid = threadIdx.x;
    if (tid < 4) sh[tid] = 0.f;
    {
        int c = tid;
        float s = 0.f, q = 0.f;
#pragma unroll
        for (int k = 0; k < 8; ++k) { s += st[k * STREP + c]; q += st[k * STREP + 256 + c]; }
        float mu = s * invN;
        float var = fmaf(q, invN, -mu * mu);
        float a = g[c] * rsqrtf(var + 1e-5f);
        la[c] = a;
        lc[c] = fmaf(-mu, a, be[c]);
    }
    __syncthreads();
    float p0 = 0.f, p1 = 0.f, p2 = 0.f, p3 = 0.f;
    const int VC = 642 * 256;
    for (int idx = blockIdx.x * 256 + tid; idx < VC; idx += gridDim.x * 256) {
        int c = idx & 255;
        float a = la[c], cc = lc[c];
        float w = wfc[idx];
        size_t base = ((size_t)(idx >> 8) << 10) + c;
        p0 = fmaf(w, leaky_f(fmaf(a, y[base], cc)), p0);
        p1 = fmaf(w, leaky_f(fmaf(a, y[base + 256], cc)), p1);
        p2 = fmaf(w, leaky_f(fmaf(a, y[base + 512], cc)), p2);
        p3 = fmaf(w, leaky_f(fmaf(a, y[base + 768], cc)), p3);
    }
    atomicAdd(&sh[0], p0);
    atomicAdd(&sh[1], p1);
    atomicAdd(&sh[2], p2);
    atomicAdd(&sh[3], p3);
    __syncthreads();
    if (tid < 4) atomicAdd(&fcacc[tid], sh[tid]);
}

__global__ void fc_finalize(const float* __restrict__ acc, const float* __restrict__ m,
                            const float* __restrict__ wm, const float* __restrict__ bm,
                            const float* __restrict__ wfc, const float* __restrict__ bfc,
                            float* __restrict__ out) {
    int b = threadIdx.x;
    if (b < 4) {
        float mv = m[b];
        float s = 0.f;
#pragma unroll
        for (int j = 0; j < 4; ++j) {
            float mm = fmaxf(fmaf(mv, wm[j], bm[j]), 0.f);
            s = fmaf(mm, wfc[642 * 256 + j], s);
        }
        out[b] = acc[b] + s + bfc[0];
    }
}

extern "C" void kernel_launch(void* const* d_in, const int* in_sizes, int n_in,
                              void* d_out, int out_size, void* d_ws, size_t ws_size,
                              hipStream_t stream) {
    const float* x = (const float*)d_in[0];
    const float* m = (const float*)d_in[1];
    const int* n0 = (const int*)d_in[2];
    const int* n1 = (const int*)d_in[3];
    const int* n2 = (const int*)d_in[4];
    const int* n3 = (const int*)d_in[5];

    // conv biases cancel exactly through batch-stats BN -> omitted.
    const float* G[8]  = {(const float*)d_in[8],  (const float*)d_in[12],
                          (const float*)d_in[16], (const float*)d_in[20],
                          (const float*)d_in[24], (const float*)d_in[28],
                          (const float*)d_in[32], (const float*)d_in[36]};
    const float* E[8]  = {(const float*)d_in[9],  (const float*)d_in[13],
                          (const float*)d_in[17], (const float*)d_in[21],
                          (const float*)d_in[25], (const float*)d_in[29],
                          (const float*)d_in[33], (const float*)d_in[37]};
    const float* wm  = (const float*)d_in[38];
    const float* bm  = (const float*)d_in[39];
    const float* wfc = (const float*)d_in[40];
    const float* bfc = (const float*)d_in[41];

    char* wsb = (char*)d_ws;
    unsigned short* X0  = (unsigned short*)(wsb + 0 * MB);
    unsigned short* Y1  = (unsigned short*)(wsb + 2 * MB);   // raw conv1_1 out
    unsigned short* F1  = (unsigned short*)(wsb + 13 * MB);  // finished conv1_1
    unsigned short* Y2  = (unsigned short*)(wsb + 24 * MB);  // raw conv1_2 out
    unsigned short* P1  = (unsigned short*)(wsb + 35 * MB);  // finished pool1
    unsigned short* Y21 = (unsigned short*)(wsb + 38 * MB);  // raw conv2_1
    unsigned short* F21 = (unsigned short*)(wsb + 44 * MB);  // finished conv2_1
    unsigned short* Y22 = (unsigned short*)(wsb + 50 * MB);  // raw conv2_2
    unsigned short* P2  = (unsigned short*)(wsb + 56 * MB);  // finished pool2
    unsigned short* WP  = (unsigned short*)(wsb + 58 * MB);
    float* part = (float*)(wsb + 64 * MB);
    float* Z31  = (float*)(wsb + 66 * MB);                   // zeroed
    float* Z32  = (float*)(wsb + 72 * MB);                   // zeroed
    float* Z41  = (float*)(wsb + 78 * MB);                   // zeroed
    float* Z42  = (float*)(wsb + 81 * MB);                   // zeroed
    float* st   = (float*)(wsb + 84 * MB);                   // zeroed (8x4096)
    float* fcacc = (float*)(wsb + 84 * MB + 131072);         // zeroed
    unsigned short* F31 = (unsigned short*)(wsb + 85 * MB);
    unsigned short* F32 = (unsigned short*)(wsb + 88 * MB);
    unsigned short* P3  = (unsigned short*)(wsb + 91 * MB);
    unsigned short* F41 = (unsigned short*)(wsb + 92 * MB);

    static const int wp_off[8] = {0, 3072, 22528, 61440, 139264, 303104, 614400, 1269760};

    const float iN1 = 1.f / (40962.f * 4.f);
    const float iN2 = 1.f / (10242.f * 4.f);
    const float iN3 = 1.f / (2562.f * 4.f);
    const float iN4 = 1.f / (642.f * 4.f);

    hipMemsetAsync(wsb + 66 * MB, 0, 18 * MB + 131072 + 16, stream);
    cast_x<<<2561, 256, 0, stream>>>(x, X0, 40962 * 16);
    prepack_all<<<9824, 256, 0, stream>>>((const float*)d_in[6], (const float*)d_in[10],
                                          (const float*)d_in[14], (const float*)d_in[18],
                                          (const float*)d_in[22], (const float*)d_in[26],
                                          (const float*)d_in[30], (const float*)d_in[34], WP);

    // ---- Level 1 (V=40962) ----
    conv1_mfma<<<2561, 256, 0, stream>>>(X0, n0, WP + wp_off[0], Y1, part, 40962);
    reduce_stats<<<64, 256, 0, stream>>>(part, st + 0 * 4096, 2561);
    finalize_kernel<32, true><<<5121, 256, 0, stream>>>(Y1, st + 0 * 4096, G[0], E[0], iN1,
                                                        F1, 1310784);
    // conv1_2: T8=5121, ST=1281, perx=321, grid=2568
    conv_mfma<32, 32, 2, 19, 1, true><<<2568, 256, 0, stream>>>(
        F1, n0, WP + wp_off[1], Y2, part, 40962, 321);
    reduce_stats<<<64, 256, 0, stream>>>(part, st + 1 * 4096, 2568);
    pool_kernel<32, true><<<1281, 256, 0, stream>>>(Y2, n0, st + 1 * 4096, G[1], E[1], iN1,
                                                    P1, 10242 * 4 * 8);

    // ---- Level 2 (V=10242) ----  T8=1281, ST=321, perx=81, grid=648
    conv_mfma<32, 64, 4, 19, 1, true><<<648, 256, 0, stream>>>(
        P1, n1, WP + wp_off[2], Y21, part, 10242, 81);
    reduce_stats<<<128, 256, 0, stream>>>(part, st + 2 * 4096, 648);
    finalize_kernel<64, true><<<2561, 256, 0, stream>>>(Y21, st + 2 * 4096, G[2], E[2], iN2,
                                                        F21, 655488);
    conv_mfma<64, 64, 4, 38, 1, true><<<648, 256, 0, stream>>>(
        F21, n1, WP + wp_off[3], Y22, part, 10242, 81);
    reduce_stats<<<128, 256, 0, stream>>>(part, st + 3 * 4096, 648);
    pool_kernel<64, true><<<641, 256, 0, stream>>>(Y22, n1, st + 3 * 4096, G[3], E[3], iN2,
                                                   P2, 2562 * 4 * 16);

    // ---- Level 3 (V=2562) ----  T8=321, ST=81, NGRP=2, SPLIT=4, perx=162, grid=1296
    conv_mfma<64, 128, 4, 10, 4, false><<<1296, 256, 0, stream>>>(
        P2, n2, WP + wp_off[4], Z31, nullptr, 2562, 162);
    stats_kernel<128><<<480, 256, 0, stream>>>(Z31, st + 4 * 4096, 10248);
    finalize_kernel<128, false><<<1281, 256, 0, stream>>>(Z31, st + 4 * 4096, G[4], E[4], iN3,
                                                          F31, 327936);
    conv_mfma<128, 128, 4, 19, 4, false><<<1296, 256, 0, stream>>>(
        F31, n2, WP + wp_off[5], Z32, nullptr, 2562, 162);
    stats_kernel<128><<<480, 256, 0, stream>>>(Z32, st + 5 * 4096, 10248);
    finalize_kernel<128, false><<<1281, 256, 0, stream>>>(Z32, st + 5 * 4096, G[5], E[5], iN3,
                                                          F32, 327936);
    pool_kernel<128, false><<<321, 256, 0, stream>>>(F32, n2, nullptr, nullptr, nullptr, 0.f,
                                                     P3, 642 * 4 * 32);

    // ---- Level 4 (V=642) ----  T8=81, ST=21, NGRP=4, SPLIT=8, perx=168, grid=1344
    conv_mfma<128, 256, 4, 10, 8, false><<<1344, 256, 0, stream>>>(
        P3, n3, WP + wp_off[6], Z41, nullptr, 642, 168);
    stats_kernel<256><<<480, 256, 0, stream>>>(Z41, st + 6 * 4096, 2568);
    finalize_kernel<256, false><<<642, 256, 0, stream>>>(Z41, st + 6 * 4096, G[6], E[6], iN4,
                                                         F41, 164352);
    conv_mfma<256, 256, 4, 19, 8, false><<<1344, 256, 0, stream>>>(
        F41, n3, WP + wp_off[7], Z42, nullptr, 642, 168);
    stats_kernel<256><<<480, 256, 0, stream>>>(Z42, st + 7 * 4096, 2568);

    // ---- FC ----
    fc_partial<<<128, 256, 0, stream>>>(Z42, wfc, st + 7 * 4096, G[7], E[7], iN4, fcacc);
    fc_finalize<<<1, 64, 0, stream>>>(fcacc, m, wm, bm, wfc, bfc, (float*)d_out);
}

// Round 11
// 493.887 us; speedup vs baseline: 1.0357x; 1.0357x over previous
//
#include <hip/hip_runtime.h>

typedef short bf16x8 __attribute__((ext_vector_type(8)));
typedef float f32x4 __attribute__((ext_vector_type(4)));

#define STREP 512
#define MB 1048576

__device__ __forceinline__ float leaky_f(float z) { return fmaxf(z, 0.2f * z); }
__device__ __forceinline__ unsigned short f2b(float f) {
    unsigned u = __float_as_uint(f);
    return (unsigned short)((u + 0x7fffu + ((u >> 16) & 1u)) >> 16);  // RTNE
}
__device__ __forceinline__ float b2f(unsigned short h) {
    return __uint_as_float(((unsigned)h) << 16);
}

// ---------------------------------------------------------------------------
// x fp32 [V][4ci][4b] -> bf16 [V][4b][4ci]
// ---------------------------------------------------------------------------
__global__ __launch_bounds__(256) void cast_x(const float* __restrict__ x,
                                              unsigned short* __restrict__ out, int total) {
    int idx = blockIdx.x * 256 + threadIdx.x;
    if (idx >= total) return;
    int v = idx >> 4, b = (idx >> 2) & 3, ci = idx & 3;
    out[idx] = f2b(x[(size_t)v * 16 + ci * 4 + b]);
}

// ---------------------------------------------------------------------------
// All 8 weight prepacks in ONE launch (B-fragment order, zero-padded chunks)
// ---------------------------------------------------------------------------
__global__ __launch_bounds__(256) void prepack_all(
    const float* __restrict__ w0, const float* __restrict__ w1,
    const float* __restrict__ w2, const float* __restrict__ w3,
    const float* __restrict__ w4, const float* __restrict__ w5,
    const float* __restrict__ w6, const float* __restrict__ w7,
    unsigned short* __restrict__ WP) {
    int gid = blockIdx.x * 256 + threadIdx.x;  // < 2514944
    const float* W;
    int base, KC, NT;
    if (gid < 3072)        { W = w0; base = 0;       KC = 76;   NT = 2; }
    else if (gid < 22528)  { W = w1; base = 3072;    KC = 608;  NT = 2; }
    else if (gid < 61440)  { W = w2; base = 22528;   KC = 608;  NT = 4; }
    else if (gid < 139264) { W = w3; base = 61440;   KC = 1216; NT = 4; }
    else if (gid < 303104) { W = w4; base = 139264;  KC = 1216; NT = 8; }
    else if (gid < 614400) { W = w5; base = 303104;  KC = 2432; NT = 8; }
    else if (gid < 1269760){ W = w6; base = 614400;  KC = 2432; NT = 16; }
    else                   { W = w7; base = 1269760; KC = 4864; NT = 16; }
    int idx = gid - base;
    int j = idx & 7, lane = (idx >> 3) & 63, q = idx >> 9;
    int nt = q % NT, chunk = q / NT;
    int kc = chunk * 32 + (lane >> 4) * 8 + j;
    int cout = nt * 16 + (lane & 15);
    float v = (kc < KC) ? W[(size_t)cout * KC + kc] : 0.f;
    WP[gid] = f2b(v);
}

// ---------------------------------------------------------------------------
// Pair-tile MFMA conv on finished bf16 [V][4][C]. M-tile = 8 vertices x 2
// batches (pair p = xcd>>2 pinned). Block = 4 waves = 4 tiles.
// COALESCED GATHER: per K-chunk the tile needs 16 segments x 64 B; lane l
// cooperatively loads seg l>>2, 16 B at sub=(l&3) -> 4 consecutive lanes form
// one 64-B (128-B for CIN=32) line request: 4-8x fewer L2 requests than the
// per-fragment gather. Bounce via wave-private padded LDS (stride 80 B ->
// 2-way conflicts = free), ds_read_b128 the MFMA fragment, MFMA.
// No barriers in the K-loop (LDS region is wave-private).
// FUSE: raw bf16 store + per-block partial stats. !FUSE: split-K atomicAdd.
// ---------------------------------------------------------------------------
template <int CIN, int COUT, int NG, int CPS, int SPLIT, bool FUSE>
__global__ __launch_bounds__(256, 4) void conv_mfma(
    const unsigned short* __restrict__ act, const int* __restrict__ neigh,
    const unsigned short* __restrict__ wp, void* __restrict__ yout,
    float* __restrict__ opart, int V, int perx) {
    constexpr int LOGC = (CIN == 32) ? 5 : (CIN == 64) ? 6 : (CIN == 128) ? 7 : 8;
    constexpr int NT = COUT / 16;
    constexpr int NGRP = NT / NG;
    constexpr int G = 4;                        // chunks staged per group
    constexpr int NGR = (CPS + G - 1) / G;
    constexpr int CSTRIDE = 16 * 80;            // 16 segs x 80 B (64+16 pad)
    __shared__ __align__(16) unsigned char stg[4][G * CSTRIDE];
    __shared__ int shn[4 * 152];
    __shared__ float ss[FUSE ? 2 * COUT : 1];
    const int T8 = (V + 7) >> 3;
    const int ST = (T8 + 3) >> 2;
    const int L = ST * NGRP * SPLIT;
    const int xcd = blockIdx.x & 7;
    const int p = xcd >> 2;
    const int li = (xcd & 3) * perx + (blockIdx.x >> 3);
    const int tid = threadIdx.x;
    if (li >= L) {
        if constexpr (FUSE) {
            float* pb = opart + (size_t)blockIdx.x * (2 * COUT);
            for (int t = tid; t < 2 * COUT; t += 256) pb[t] = 0.f;
        }
        return;
    }
    const int sp = li % SPLIT;
    const int t1 = li / SPLIT;
    const int ng = t1 % NGRP;
    const int stile = t1 / NGRP;
    const int lane = tid & 63, wib = tid >> 6;
    const int v0 = (stile * 4 + wib) * 8;
    const int m = lane & 15, quad = lane >> 4;
    // load-side decomposition: seg = (vi,bb), 4 lanes x 16 B per seg
    const int segL = lane >> 2, subL = lane & 3;
    const int viL = segL >> 1, bbL = segL & 1;
    int* sn = shn + wib * 152;
    {
        const int lim = V * 19 - 1;
        for (int t = lane; t < 152; t += 64) {
            int src = v0 * 19 + t;
            sn[t] = neigh[src < lim ? src : lim];
        }
    }
    if constexpr (FUSE) {
        for (int t = tid; t < 2 * COUT; t += 256) ss[t] = 0.f;
    }
    __syncthreads();

    const unsigned short* wl = wp + ((size_t)(ng * NG) * 64 + lane) * 8;
    const int c0 = sp * CPS;
    unsigned char* myst = stg[wib];

    f32x4 acc[NG];
#pragma unroll
    for (int t = 0; t < NG; ++t) acc[t] = (f32x4){0.f, 0.f, 0.f, 0.f};

#pragma unroll
    for (int gi = 0; gi < NGR; ++gi) {
        uint4 ld[G];
        // 1) coalesced cooperative loads (4 lanes = one 64-B row segment)
#pragma unroll
        for (int i = 0; i < G; ++i) {
            const int chl = gi * G + i;
            if (chl < CPS) {
                const int ch = c0 + chl;
                int k_nb = (ch * 32) >> LOGC;
                k_nb = k_nb < 18 ? k_nb : 18;   // zero-padded chunk clamp
                const int ci = (ch * 32) & (CIN - 1);
                const int n = sn[viL * 19 + k_nb];
                ld[i] = *(const uint4*)(act + ((size_t)n * 4 + p * 2 + bbL) * CIN
                                        + ci + subL * 8);
            }
        }
        __builtin_amdgcn_sched_barrier(0);
        // 2) LDS bounce (padded: seg stride 80 B)
#pragma unroll
        for (int i = 0; i < G; ++i) {
            if (gi * G + i < CPS)
                *(uint4*)(myst + i * CSTRIDE + segL * 80 + subL * 16) = ld[i];
        }
        __builtin_amdgcn_sched_barrier(0);
        // 3) fragment read + MFMA (read seg m, bytes quad*16..+16)
#pragma unroll
        for (int i = 0; i < G; ++i) {
            const int chl = gi * G + i;
            if (chl < CPS) {
                bf16x8 a = *(const bf16x8*)(myst + i * CSTRIDE + m * 80 + quad * 16);
                const unsigned short* wc = wl + (size_t)(c0 + chl) * NT * 512;
#pragma unroll
                for (int t = 0; t < NG; ++t) {
                    bf16x8 bfv = *(const bf16x8*)(wc + (size_t)t * 512);
                    acc[t] = __builtin_amdgcn_mfma_f32_16x16x32_bf16(a, bfv, acc[t], 0, 0, 0);
                }
            }
        }
    }

    // C/D row = quad*4+r -> v = v0 + quad*2 + (r>>1), batch = p*2 + (r&1)
    if constexpr (FUSE) {
        unsigned short* y = (unsigned short*)yout;
        float sl[NG], ql[NG];
#pragma unroll
        for (int t = 0; t < NG; ++t) { sl[t] = 0.f; ql[t] = 0.f; }
#pragma unroll
        for (int r = 0; r < 4; ++r) {
            int v = v0 + quad * 2 + (r >> 1);
            if (v < V) {
                size_t row = ((size_t)v * 4 + p * 2 + (r & 1)) * COUT;
#pragma unroll
                for (int t = 0; t < NG; ++t) {
                    int cout = (ng * NG + t) * 16 + m;
                    float val = acc[t][r];
                    y[row + cout] = f2b(val);
                    sl[t] += val;
                    ql[t] = fmaf(val, val, ql[t]);
                }
            }
        }
#pragma unroll
        for (int t = 0; t < NG; ++t) {
            int cout = (ng * NG + t) * 16 + m;
            atomicAdd(&ss[cout], sl[t]);
            atomicAdd(&ss[COUT + cout], ql[t]);
        }
        __syncthreads();
        float* pb = opart + (size_t)blockIdx.x * (2 * COUT);
        for (int t = tid; t < 2 * COUT; t += 256) pb[t] = ss[t];
    } else {
        float* y = (float*)yout;
#pragma unroll
        for (int r = 0; r < 4; ++r) {
            int v = v0 + quad * 2 + (r >> 1);
            if (v < V) {
                size_t row = ((size_t)v * 4 + p * 2 + (r & 1)) * COUT;
#pragma unroll
                for (int t = 0; t < NG; ++t)
                    atomicAdd(&y[row + (ng * NG + t) * 16 + m], acc[t][r]);
            }
        }
    }
}

// ---------------------------------------------------------------------------
// conv1_1: CIN=4, quad-tile (4 vertices x 4 batches). Loads already coalesce
// 4 consecutive lanes (batch-adjacent) -> 32-B requests; keep as-is.
// ---------------------------------------------------------------------------
__global__ __launch_bounds__(256) void conv1_mfma(
    const unsigned short* __restrict__ act, const int* __restrict__ neigh,
    const unsigned short* __restrict__ wp, unsigned short* __restrict__ y,
    float* __restrict__ opart, int V) {
    __shared__ int shn[4 * 76];
    __shared__ float ss[64];
    const int tid = threadIdx.x;
    const int lane = tid & 63, wib = tid >> 6;
    const int v0 = (blockIdx.x * 4 + wib) * 4;
    const int m = lane & 15, quad = lane >> 4;
    int* sn = shn + wib * 76;
    {
        const int lim = V * 19 - 1;
        for (int t = lane; t < 76; t += 64) {
            int src = v0 * 19 + t;
            sn[t] = neigh[src < lim ? src : lim];
        }
    }
    for (int t = tid; t < 64; t += 256) ss[t] = 0.f;
    __syncthreads();

    const unsigned short* wl = wp + (size_t)lane * 8;
    const int b = m & 3, vq = m >> 2;

    f32x4 acc[2] = {(f32x4){0.f, 0.f, 0.f, 0.f}, (f32x4){0.f, 0.f, 0.f, 0.f}};
    union { unsigned u[4]; bf16x8 v; } w[3];
    bf16x8 bfr[3][2];
#pragma unroll
    for (int ch = 0; ch < 3; ++ch) {
        int k0 = (ch * 32 + quad * 8) >> 2;
        int k0c = k0 < 18 ? k0 : 18;
        int k1c = k0 + 1 < 18 ? k0 + 1 : 18;
        const unsigned* p0 = (const unsigned*)(act + ((size_t)sn[vq * 19 + k0c] * 4 + b) * 4);
        const unsigned* p1 = (const unsigned*)(act + ((size_t)sn[vq * 19 + k1c] * 4 + b) * 4);
        w[ch].u[0] = p0[0]; w[ch].u[1] = p0[1];
        w[ch].u[2] = p1[0]; w[ch].u[3] = p1[1];   // OOB k: weights zero-padded
#pragma unroll
        for (int t = 0; t < 2; ++t)
            bfr[ch][t] = *(const bf16x8*)(wl + (size_t)ch * 1024 + (size_t)t * 512);
    }
    __builtin_amdgcn_sched_barrier(0);
#pragma unroll
    for (int ch = 0; ch < 3; ++ch)
#pragma unroll
        for (int t = 0; t < 2; ++t)
            acc[t] = __builtin_amdgcn_mfma_f32_16x16x32_bf16(w[ch].v, bfr[ch][t], acc[t], 0, 0, 0);

    float sl[2] = {0.f, 0.f}, ql[2] = {0.f, 0.f};
    int v = v0 + quad;
    if (v < V) {
        size_t rb = (size_t)v * 4 * 32;
#pragma unroll
        for (int r = 0; r < 4; ++r) {
#pragma unroll
            for (int t = 0; t < 2; ++t) {
                float val = acc[t][r];
                y[rb + (size_t)r * 32 + t * 16 + m] = f2b(val);
                sl[t] += val;
                ql[t] = fmaf(val, val, ql[t]);
            }
        }
    }
#pragma unroll
    for (int t = 0; t < 2; ++t) {
        atomicAdd(&ss[t * 16 + m], sl[t]);
        atomicAdd(&ss[32 + t * 16 + m], ql[t]);
    }
    __syncthreads();
    float* pb = opart + (size_t)blockIdx.x * 64;
    for (int t = tid; t < 64; t += 256) pb[t] = ss[t];
}

// ---------------------------------------------------------------------------
// Sum per-block partials: grid.x = 2*C; st[c] = sum_b part[b][c]
// ---------------------------------------------------------------------------
__global__ __launch_bounds__(256) void reduce_stats(const float* __restrict__ part,
                                                    float* __restrict__ st, int nblk) {
    __shared__ float red[256];
    int c = blockIdx.x;
    int C2 = gridDim.x;
    float s = 0.f;
    for (int b = threadIdx.x; b < nblk; b += 256) s += part[(size_t)b * C2 + c];
    red[threadIdx.x] = s;
    __syncthreads();
    for (int off = 128; off > 0; off >>= 1) {
        if (threadIdx.x < off) red[threadIdx.x] += red[threadIdx.x + off];
        __syncthreads();
    }
    if (threadIdx.x == 0) st[c] = red[0];
}

// ---------------------------------------------------------------------------
// Per-channel sum/sumsq of fp32 y [rows][C] -> per-XCD replicated stats
// ---------------------------------------------------------------------------
template <int C>
__global__ __launch_bounds__(256) void stats_kernel(const float* __restrict__ y,
                                                    float* __restrict__ st, int rows) {
    constexpr int LOGC = (C == 128) ? 7 : 8;
    __shared__ float ss[2 * C];
    int tid = threadIdx.x;
    for (int i = tid; i < 2 * C; i += 256) ss[i] = 0.f;
    __syncthreads();
    int c = tid & (C - 1);
    const int rpb = 256 >> LOGC;
    float s = 0.f, q = 0.f;
    for (int r = blockIdx.x * rpb + (tid >> LOGC); r < rows; r += gridDim.x * rpb) {
        float v = y[(size_t)r * C + c];
        s += v;
        q = fmaf(v, v, q);
    }
    atomicAdd(&ss[c], s);
    atomicAdd(&ss[C + c], q);
    __syncthreads();
    float* orep = st + (blockIdx.x & 7) * STREP;
    for (int i = tid; i < 2 * C; i += 256) atomicAdd(&orep[i], ss[i]);
}

// ---------------------------------------------------------------------------
// bnleaky -> finished bf16. BIN: raw bf16 in (plain stats). !BIN: fp32 in
// (replicated stats).
// ---------------------------------------------------------------------------
template <int C, bool BIN>
__global__ __launch_bounds__(256) void finalize_kernel(
    const void* __restrict__ yin, const float* __restrict__ st,
    const float* __restrict__ g, const float* __restrict__ be, float invN,
    unsigned short* __restrict__ out, int total4) {
    __shared__ float la[C], lc[C];
    int tid = threadIdx.x;
    for (int c = tid; c < C; c += 256) {
        float s, q;
        if constexpr (BIN) {
            s = st[c]; q = st[C + c];
        } else {
            s = 0.f; q = 0.f;
#pragma unroll
            for (int k = 0; k < 8; ++k) { s += st[k * STREP + c]; q += st[k * STREP + C + c]; }
        }
        float mu = s * invN;
        float var = fmaf(q, invN, -mu * mu);
        float a = g[c] * rsqrtf(var + 1e-5f);
        la[c] = a;
        lc[c] = fmaf(-mu, a, be[c]);
    }
    __syncthreads();
    int idx = blockIdx.x * 256 + tid;
    if (idx >= total4) return;
    int c0 = (idx * 4) & (C - 1);
    float v0, v1, v2, v3;
    if constexpr (BIN) {
        uint2 d = ((const uint2*)yin)[idx];
        v0 = b2f((unsigned short)(d.x & 0xffff));
        v1 = b2f((unsigned short)(d.x >> 16));
        v2 = b2f((unsigned short)(d.y & 0xffff));
        v3 = b2f((unsigned short)(d.y >> 16));
    } else {
        float4 yv = ((const float4*)yin)[idx];
        v0 = yv.x; v1 = yv.y; v2 = yv.z; v3 = yv.w;
    }
    float o0 = leaky_f(fmaf(la[c0 + 0], v0, lc[c0 + 0]));
    float o1 = leaky_f(fmaf(la[c0 + 1], v1, lc[c0 + 1]));
    float o2 = leaky_f(fmaf(la[c0 + 2], v2, lc[c0 + 2]));
    float o3 = leaky_f(fmaf(la[c0 + 3], v3, lc[c0 + 3]));
    unsigned r0 = (unsigned)f2b(o0) | ((unsigned)f2b(o1) << 16);
    unsigned r1 = (unsigned)f2b(o2) | ((unsigned)f2b(o3) << 16);
    ((uint2*)out)[idx] = make_uint2(r0, r1);
}

// ---------------------------------------------------------------------------
// Mean-pool on [Vin][4][C] -> [VP][4][C]. BN: producer bnleaky at gather.
// ---------------------------------------------------------------------------
template <int C, bool BN>
__global__ __launch_bounds__(256) void pool_kernel(
    const unsigned short* __restrict__ in, const int* __restrict__ neigh,
    const float* __restrict__ pstats, const float* __restrict__ pg,
    const float* __restrict__ pe, float invN,
    unsigned short* __restrict__ out, int total) {
    constexpr int LC4 = (C == 32) ? 3 : (C == 64) ? 4 : 5;
    __shared__ float2 lac[BN ? C : 1];
    int tid = threadIdx.x;
    if constexpr (BN) {
        for (int c = tid; c < C; c += 256) {
            float s = pstats[c], q = pstats[C + c];
            float mu = s * invN;
            float var = fmaf(q, invN, -mu * mu);
            float a = pg[c] * rsqrtf(var + 1e-5f);
            lac[c] = make_float2(a, fmaf(-mu, a, pe[c]));
        }
        __syncthreads();
    }
    int idx = blockIdx.x * 256 + tid;
    if (idx >= total) return;
    int c4 = idx & ((C / 4) - 1);
    int b = (idx >> LC4) & 3;
    int vp = idx >> (LC4 + 2);
    float a0 = 0.f, a1 = 0.f, a2 = 0.f, a3 = 0.f;
    for (int k = 0; k < 19; ++k) {
        int n = neigh[vp * 19 + k];
        uint2 d = *(const uint2*)(in + ((size_t)n * 4 + b) * C + c4 * 4);
        float f0 = b2f((unsigned short)(d.x & 0xffff));
        float f1 = b2f((unsigned short)(d.x >> 16));
        float f2 = b2f((unsigned short)(d.y & 0xffff));
        float f3 = b2f((unsigned short)(d.y >> 16));
        if constexpr (BN) {
            float2 t0 = lac[c4 * 4 + 0], t1 = lac[c4 * 4 + 1];
            float2 t2 = lac[c4 * 4 + 2], t3 = lac[c4 * 4 + 3];
            f0 = leaky_f(fmaf(f0, t0.x, t0.y));
            f1 = leaky_f(fmaf(f1, t1.x, t1.y));
            f2 = leaky_f(fmaf(f2, t2.x, t2.y));
            f3 = leaky_f(fmaf(f3, t3.x, t3.y));
        }
        a0 += f0; a1 += f1; a2 += f2; a3 += f3;
    }
    const float r = 1.f / 19.f;
    unsigned r0 = (unsigned)f2b(a0 * r) | ((unsigned)f2b(a1 * r) << 16);
    unsigned r1 = (unsigned)f2b(a2 * r) | ((unsigned)f2b(a3 * r) << 16);
    ((uint2*)out)[idx] = make_uint2(r0, r1);
}

// ---------------------------------------------------------------------------
// FC over bnleaky(y4_2 fp32 [642][4][256], replicated stats)
// ---------------------------------------------------------------------------
__global__ __launch_bounds__(256) void fc_partial(
    const float* __restrict__ y, const float* __restrict__ wfc,
    const float* __restrict__ st, const float* __restrict__ g,
    const float* __restrict__ be, float invN, float* __restrict__ fcacc) {
    __shared__ float la[256], lc[256];
    __shared__ float sh[4];
    int tid = threadIdx.x;
    if (tid < 4) sh[tid] = 0.f;
    {
        int c = tid;
        float s = 0.f, q = 0.f;
#pragma unroll
        for (int k = 0; k < 8; ++k) { s += st[k * STREP + c]; q += st[k * STREP + 256 + c]; }
        float mu = s * invN;
        float var = fmaf(q, invN, -mu * mu);
        float a = g[c] * rsqrtf(var + 1e-5f);
        la[c] = a;
        lc[c] = fmaf(-mu, a, be[c]);
    }
    __syncthreads();
    float p0 = 0.f, p1 = 0.f, p2 = 0.f, p3 = 0.f;
    const int VC = 642 * 256;
    for (int idx = blockIdx.x * 256 + tid; idx < VC; idx += gridDim.x * 256) {
        int c = idx & 255;
        float a = la[c], cc = lc[c];
        float w = wfc[idx];
        size_t base = ((size_t)(idx >> 8) << 10) + c;
        p0 = fmaf(w, leaky_f(fmaf(a, y[base], cc)), p0);
        p1 = fmaf(w, leaky_f(fmaf(a, y[base + 256], cc)), p1);
        p2 = fmaf(w, leaky_f(fmaf(a, y[base + 512], cc)), p2);
        p3 = fmaf(w, leaky_f(fmaf(a, y[base + 768], cc)), p3);
    }
    atomicAdd(&sh[0], p0);
    atomicAdd(&sh[1], p1);
    atomicAdd(&sh[2], p2);
    atomicAdd(&sh[3], p3);
    __syncthreads();
    if (tid < 4) atomicAdd(&fcacc[tid], sh[tid]);
}

__global__ void fc_finalize(const float* __restrict__ acc, const float* __restrict__ m,
                            const float* __restrict__ wm, const float* __restrict__ bm,
                            const float* __restrict__ wfc, const float* __restrict__ bfc,
                            float* __restrict__ out) {
    int b = threadIdx.x;
    if (b < 4) {
        float mv = m[b];
        float s = 0.f;
#pragma unroll
        for (int j = 0; j < 4; ++j) {
            float mm = fmaxf(fmaf(mv, wm[j], bm[j]), 0.f);
            s = fmaf(mm, wfc[642 * 256 + j], s);
        }
        out[b] = acc[b] + s + bfc[0];
    }
}

extern "C" void kernel_launch(void* const* d_in, const int* in_sizes, int n_in,
                              void* d_out, int out_size, void* d_ws, size_t ws_size,
                              hipStream_t stream) {
    const float* x = (const float*)d_in[0];
    const float* m = (const float*)d_in[1];
    const int* n0 = (const int*)d_in[2];
    const int* n1 = (const int*)d_in[3];
    const int* n2 = (const int*)d_in[4];
    const int* n3 = (const int*)d_in[5];

    // conv biases cancel exactly through batch-stats BN -> omitted.
    const float* G[8]  = {(const float*)d_in[8],  (const float*)d_in[12],
                          (const float*)d_in[16], (const float*)d_in[20],
                          (const float*)d_in[24], (const float*)d_in[28],
                          (const float*)d_in[32], (const float*)d_in[36]};
    const float* E[8]  = {(const float*)d_in[9],  (const float*)d_in[13],
                          (const float*)d_in[17], (const float*)d_in[21],
                          (const float*)d_in[25], (const float*)d_in[29],
                          (const float*)d_in[33], (const float*)d_in[37]};
    const float* wm  = (const float*)d_in[38];
    const float* bm  = (const float*)d_in[39];
    const float* wfc = (const float*)d_in[40];
    const float* bfc = (const float*)d_in[41];

    char* wsb = (char*)d_ws;
    unsigned short* X0  = (unsigned short*)(wsb + 0 * MB);
    unsigned short* Y1  = (unsigned short*)(wsb + 2 * MB);   // raw conv1_1 out
    unsigned short* F1  = (unsigned short*)(wsb + 13 * MB);  // finished conv1_1
    unsigned short* Y2  = (unsigned short*)(wsb + 24 * MB);  // raw conv1_2 out
    unsigned short* P1  = (unsigned short*)(wsb + 35 * MB);  // finished pool1
    unsigned short* Y21 = (unsigned short*)(wsb + 38 * MB);  // raw conv2_1
    unsigned short* F21 = (unsigned short*)(wsb + 44 * MB);  // finished conv2_1
    unsigned short* Y22 = (unsigned short*)(wsb + 50 * MB);  // raw conv2_2
    unsigned short* P2  = (unsigned short*)(wsb + 56 * MB);  // finished pool2
    unsigned short* WP  = (unsigned short*)(wsb + 58 * MB);
    float* part = (float*)(wsb + 64 * MB);
    float* Z31  = (float*)(wsb + 66 * MB);                   // zeroed
    float* Z32  = (float*)(wsb + 72 * MB);                   // zeroed
    float* Z41  = (float*)(wsb + 78 * MB);                   // zeroed
    float* Z42  = (float*)(wsb + 81 * MB);                   // zeroed
    float* st   = (float*)(wsb + 84 * MB);                   // zeroed (8x4096)
    float* fcacc = (float*)(wsb + 84 * MB + 131072);         // zeroed
    unsigned short* F31 = (unsigned short*)(wsb + 85 * MB);
    unsigned short* F32 = (unsigned short*)(wsb + 88 * MB);
    unsigned short* P3  = (unsigned short*)(wsb + 91 * MB);
    unsigned short* F41 = (unsigned short*)(wsb + 92 * MB);

    static const int wp_off[8] = {0, 3072, 22528, 61440, 139264, 303104, 614400, 1269760};

    const float iN1 = 1.f / (40962.f * 4.f);
    const float iN2 = 1.f / (10242.f * 4.f);
    const float iN3 = 1.f / (2562.f * 4.f);
    const float iN4 = 1.f / (642.f * 4.f);

    hipMemsetAsync(wsb + 66 * MB, 0, 18 * MB + 131072 + 16, stream);
    cast_x<<<2561, 256, 0, stream>>>(x, X0, 40962 * 16);
    prepack_all<<<9824, 256, 0, stream>>>((const float*)d_in[6], (const float*)d_in[10],
                                          (const float*)d_in[14], (const float*)d_in[18],
                                          (const float*)d_in[22], (const float*)d_in[26],
                                          (const float*)d_in[30], (const float*)d_in[34], WP);

    // ---- Level 1 (V=40962) ----
    conv1_mfma<<<2561, 256, 0, stream>>>(X0, n0, WP + wp_off[0], Y1, part, 40962);
    reduce_stats<<<64, 256, 0, stream>>>(part, st + 0 * 4096, 2561);
    finalize_kernel<32, true><<<5121, 256, 0, stream>>>(Y1, st + 0 * 4096, G[0], E[0], iN1,
                                                        F1, 1310784);
    // conv1_2: T8=5121, ST=1281, perx=321, grid=2568
    conv_mfma<32, 32, 2, 19, 1, true><<<2568, 256, 0, stream>>>(
        F1, n0, WP + wp_off[1], Y2, part, 40962, 321);
    reduce_stats<<<64, 256, 0, stream>>>(part, st + 1 * 4096, 2568);
    pool_kernel<32, true><<<1281, 256, 0, stream>>>(Y2, n0, st + 1 * 4096, G[1], E[1], iN1,
                                                    P1, 10242 * 4 * 8);

    // ---- Level 2 (V=10242) ----  T8=1281, ST=321, perx=81, grid=648
    conv_mfma<32, 64, 4, 19, 1, true><<<648, 256, 0, stream>>>(
        P1, n1, WP + wp_off[2], Y21, part, 10242, 81);
    reduce_stats<<<128, 256, 0, stream>>>(part, st + 2 * 4096, 648);
    finalize_kernel<64, true><<<2561, 256, 0, stream>>>(Y21, st + 2 * 4096, G[2], E[2], iN2,
                                                        F21, 655488);
    conv_mfma<64, 64, 4, 38, 1, true><<<648, 256, 0, stream>>>(
        F21, n1, WP + wp_off[3], Y22, part, 10242, 81);
    reduce_stats<<<128, 256, 0, stream>>>(part, st + 3 * 4096, 648);
    pool_kernel<64, true><<<641, 256, 0, stream>>>(Y22, n1, st + 3 * 4096, G[3], E[3], iN2,
                                                   P2, 2562 * 4 * 16);

    // ---- Level 3 (V=2562) ----  T8=321, ST=81, NGRP=2, SPLIT=4, perx=162, grid=1296
    conv_mfma<64, 128, 4, 10, 4, false><<<1296, 256, 0, stream>>>(
        P2, n2, WP + wp_off[4], Z31, nullptr, 2562, 162);
    stats_kernel<128><<<480, 256, 0, stream>>>(Z31, st + 4 * 4096, 10248);
    finalize_kernel<128, false><<<1281, 256, 0, stream>>>(Z31, st + 4 * 4096, G[4], E[4], iN3,
                                                          F31, 327936);
    conv_mfma<128, 128, 4, 19, 4, false><<<1296, 256, 0, stream>>>(
        F31, n2, WP + wp_off[5], Z32, nullptr, 2562, 162);
    stats_kernel<128><<<480, 256, 0, stream>>>(Z32, st + 5 * 4096, 10248);
    finalize_kernel<128, false><<<1281, 256, 0, stream>>>(Z32, st + 5 * 4096, G[5], E[5], iN3,
                                                          F32, 327936);
    pool_kernel<128, false><<<321, 256, 0, stream>>>(F32, n2, nullptr, nullptr, nullptr, 0.f,
                                                     P3, 642 * 4 * 32);

    // ---- Level 4 (V=642) ----  T8=81, ST=21, NGRP=4, SPLIT=8, perx=168, grid=1344
    conv_mfma<128, 256, 4, 10, 8, false><<<1344, 256, 0, stream>>>(
        P3, n3, WP + wp_off[6], Z41, nullptr, 642, 168);
    stats_kernel<256><<<480, 256, 0, stream>>>(Z41, st + 6 * 4096, 2568);
    finalize_kernel<256, false><<<642, 256, 0, stream>>>(Z41, st + 6 * 4096, G[6], E[6], iN4,
                                                         F41, 164352);
    conv_mfma<256, 256, 4, 19, 8, false><<<1344, 256, 0, stream>>>(
        F41, n3, WP + wp_off[7], Z42, nullptr, 642, 168);
    stats_kernel<256><<<480, 256, 0, stream>>>(Z42, st + 7 * 4096, 2568);

    // ---- FC ----
    fc_partial<<<128, 256, 0, stream>>>(Z42, wfc, st + 7 * 4096, G[7], E[7], iN4, fcacc);
    fc_finalize<<<1, 64, 0, stream>>>(fcacc, m, wm, bm, wfc, bfc, (float*)d_out);
}

// Round 12
// 489.722 us; speedup vs baseline: 1.0445x; 1.0085x over previous
//
#include <hip/hip_runtime.h>

typedef short bf16x8 __attribute__((ext_vector_type(8)));
typedef float f32x4 __attribute__((ext_vector_type(4)));

#define STREP 512
#define MB 1048576

__device__ __forceinline__ float leaky_f(float z) { return fmaxf(z, 0.2f * z); }
__device__ __forceinline__ unsigned short f2b(float f) {
    unsigned u = __float_as_uint(f);
    return (unsigned short)((u + 0x7fffu + ((u >> 16) & 1u)) >> 16);  // RTNE
}
__device__ __forceinline__ float b2f(unsigned short h) {
    return __uint_as_float(((unsigned)h) << 16);
}

// ---------------------------------------------------------------------------
// x fp32 [V][4ci][4b] -> bf16 [V][4b][4ci]
// ---------------------------------------------------------------------------
__global__ __launch_bounds__(256) void cast_x(const float* __restrict__ x,
                                              unsigned short* __restrict__ out, int total) {
    int idx = blockIdx.x * 256 + threadIdx.x;
    if (idx >= total) return;
    int v = idx >> 4, b = (idx >> 2) & 3, ci = idx & 3;
    out[idx] = f2b(x[(size_t)v * 16 + ci * 4 + b]);
}

// ---------------------------------------------------------------------------
// All 8 weight prepacks in ONE launch (B-fragment order, zero-padded chunks)
// ---------------------------------------------------------------------------
__global__ __launch_bounds__(256) void prepack_all(
    const float* __restrict__ w0, const float* __restrict__ w1,
    const float* __restrict__ w2, const float* __restrict__ w3,
    const float* __restrict__ w4, const float* __restrict__ w5,
    const float* __restrict__ w6, const float* __restrict__ w7,
    unsigned short* __restrict__ WP) {
    int gid = blockIdx.x * 256 + threadIdx.x;  // < 2514944
    const float* W;
    int base, KC, NT;
    if (gid < 3072)        { W = w0; base = 0;       KC = 76;   NT = 2; }
    else if (gid < 22528)  { W = w1; base = 3072;    KC = 608;  NT = 2; }
    else if (gid < 61440)  { W = w2; base = 22528;   KC = 608;  NT = 4; }
    else if (gid < 139264) { W = w3; base = 61440;   KC = 1216; NT = 4; }
    else if (gid < 303104) { W = w4; base = 139264;  KC = 1216; NT = 8; }
    else if (gid < 614400) { W = w5; base = 303104;  KC = 2432; NT = 8; }
    else if (gid < 1269760){ W = w6; base = 614400;  KC = 2432; NT = 16; }
    else                   { W = w7; base = 1269760; KC = 4864; NT = 16; }
    int idx = gid - base;
    int j = idx & 7, lane = (idx >> 3) & 63, q = idx >> 9;
    int nt = q % NT, chunk = q / NT;
    int kc = chunk * 32 + (lane >> 4) * 8 + j;
    int cout = nt * 16 + (lane & 15);
    float v = (kc < KC) ? W[(size_t)cout * KC + kc] : 0.f;
    WP[gid] = f2b(v);
}

// ---------------------------------------------------------------------------
// FUSE conv (levels 1-2): wave = 16 vertices x 2 batches = TWO MFMA M-tiles
// sharing B-fragments. Pair p=xcd>>2 pinned. BN: prev-layer bnleaky applied
// to gathered A-fragments. Epilogue: stats (no global atomics; per-block
// partials) + COALESCED bf16 stores via wave-private LDS (full 64B segments).
// NGRP==1 (NG == COUT/16).
// ---------------------------------------------------------------------------
template <int CIN, int NG, int CPS, bool BN>
__global__ __launch_bounds__(256, 4) void conv_fuse(
    const unsigned short* __restrict__ act, const int* __restrict__ neigh,
    const unsigned short* __restrict__ wp, unsigned short* __restrict__ y,
    float* __restrict__ opart, const float* __restrict__ pst,
    const float* __restrict__ pg, const float* __restrict__ pe,
    float invN, int V, int perx) {
    constexpr int COUT = NG * 16;
    constexpr int LOGC = (CIN == 32) ? 5 : 6;
    constexpr int GP = (NG >= 4) ? 2 : 4;
    constexpr int NGR = (CPS + GP - 1) / GP;
    __shared__ int shn[4 * 304];
    __shared__ float ss[2 * COUT];
    __shared__ float2 lac[BN ? CIN : 1];
    __shared__ __align__(16) unsigned short est[4][32 * COUT];
    const int T16 = (V + 15) >> 4;
    const int ST = (T16 + 3) >> 2;
    const int xcd = blockIdx.x & 7;
    const int p = xcd >> 2;
    const int li = (xcd & 3) * perx + (blockIdx.x >> 3);
    const int tid = threadIdx.x;
    if (li >= ST) {
        float* pb = opart + (size_t)blockIdx.x * (2 * COUT);
        for (int t = tid; t < 2 * COUT; t += 256) pb[t] = 0.f;
        return;
    }
    const int lane = tid & 63, wib = tid >> 6;
    const int v0 = (li * 4 + wib) * 16;
    const int m = lane & 15, quad = lane >> 4;
    const int vi = m >> 1, bb = m & 1;
    int* sn = shn + wib * 304;
    {
        const int lim = V * 19 - 1;
        for (int t = lane; t < 304; t += 64) {
            int src = v0 * 19 + t;
            sn[t] = neigh[src < lim ? src : lim];
        }
    }
    if constexpr (BN) {
        for (int c = tid; c < CIN; c += 256) {
            float s = pst[c], q = pst[CIN + c];
            float mu = s * invN;
            float var = fmaf(q, invN, -mu * mu);
            float a = pg[c] * rsqrtf(var + 1e-5f);
            lac[c] = make_float2(a, fmaf(-mu, a, pe[c]));
        }
    }
    for (int t = tid; t < 2 * COUT; t += 256) ss[t] = 0.f;
    __syncthreads();

    const unsigned short* wl = wp + (size_t)lane * 8;
    const int boff = p * 2 + bb;

    f32x4 acc[2][NG];
#pragma unroll
    for (int h = 0; h < 2; ++h)
#pragma unroll
        for (int t = 0; t < NG; ++t) acc[h][t] = (f32x4){0.f, 0.f, 0.f, 0.f};

#pragma unroll
    for (int gi = 0; gi < NGR; ++gi) {
        bf16x8 A[2][GP];
        bf16x8 Bf[GP][NG];
        int cia[GP];
#pragma unroll
        for (int g = 0; g < GP; ++g) {
            const int ch = gi * GP + g;
            if (ch < CPS) {
                int k_nb = (ch * 32) >> LOGC;
                k_nb = k_nb < 18 ? k_nb : 18;   // zero-padded chunk clamp
                const int ci = ((ch * 32) & (CIN - 1)) + quad * 8;
                cia[g] = ci;
#pragma unroll
                for (int h = 0; h < 2; ++h) {
                    const int n = sn[(h * 8 + vi) * 19 + k_nb];
                    A[h][g] = *(const bf16x8*)(act + ((size_t)n * 4 + boff) * CIN + ci);
                }
                const unsigned short* wc = wl + (size_t)ch * NG * 512;
#pragma unroll
                for (int t = 0; t < NG; ++t)
                    Bf[g][t] = *(const bf16x8*)(wc + (size_t)t * 512);
            }
        }
        __builtin_amdgcn_sched_barrier(0);
        if constexpr (BN) {
#pragma unroll
            for (int g = 0; g < GP; ++g) {
                if (gi * GP + g < CPS) {
#pragma unroll
                    for (int h = 0; h < 2; ++h) {
                        bf16x8 r = A[h][g];
#pragma unroll
                        for (int j = 0; j < 8; ++j) {
                            float2 t2 = lac[cia[g] + j];
                            r[j] = (short)f2b(leaky_f(fmaf(b2f((unsigned short)r[j]), t2.x, t2.y)));
                        }
                        A[h][g] = r;
                    }
                }
            }
        }
#pragma unroll
        for (int g = 0; g < GP; ++g) {
            if (gi * GP + g < CPS) {
#pragma unroll
                for (int t = 0; t < NG; ++t) {
                    acc[0][t] = __builtin_amdgcn_mfma_f32_16x16x32_bf16(A[0][g], Bf[g][t], acc[0][t], 0, 0, 0);
                    acc[1][t] = __builtin_amdgcn_mfma_f32_16x16x32_bf16(A[1][g], Bf[g][t], acc[1][t], 0, 0, 0);
                }
            }
        }
    }

    // C/D row = quad*4+r -> vertex quad*2+(r>>1), batch r&1 (within half h)
    float sl[NG], ql[NG];
#pragma unroll
    for (int t = 0; t < NG; ++t) { sl[t] = 0.f; ql[t] = 0.f; }
    unsigned short* es = est[wib];
#pragma unroll
    for (int h = 0; h < 2; ++h) {
#pragma unroll
        for (int r = 0; r < 4; ++r) {
            const int vl2 = quad * 2 + (r >> 1);
            const int v = v0 + h * 8 + vl2;
            const int seg = h * 16 + vl2 * 2 + (r & 1);
            const bool valid = (v < V);
#pragma unroll
            for (int t = 0; t < NG; ++t) {
                float val = acc[h][t][r];
                es[seg * COUT + t * 16 + m] = f2b(val);
                if (valid) { sl[t] += val; ql[t] = fmaf(val, val, ql[t]); }
            }
        }
    }
#pragma unroll
    for (int t = 0; t < NG; ++t) {
        atomicAdd(&ss[t * 16 + m], sl[t]);
        atomicAdd(&ss[COUT + t * 16 + m], ql[t]);
    }
    __syncthreads();
    // coalesced store: 32 segs x COUT*2 B; 2 lanes/seg, NG x 16B per lane
    {
        const int seg2 = lane >> 1, sub2 = lane & 1;
        const int h = seg2 >> 4, rem = seg2 & 15;
        const int vl = rem >> 1, bst = rem & 1;
        const int v = v0 + h * 8 + vl;
        if (v < V) {
            const unsigned short* src = es + seg2 * COUT + sub2 * (COUT / 2);
            unsigned short* dst = y + ((size_t)v * 4 + p * 2 + bst) * COUT + sub2 * (COUT / 2);
#pragma unroll
            for (int j = 0; j < NG; ++j)
                *(uint4*)(dst + j * 8) = *(const uint4*)(src + j * 8);
        }
    }
    float* pb = opart + (size_t)blockIdx.x * (2 * COUT);
    for (int t = tid; t < 2 * COUT; t += 256) pb[t] = ss[t];
}

// ---------------------------------------------------------------------------
// conv1_1: CIN=4, quad-tile (4 v x 4 b per wave). Raw bf16 out (coalesced via
// LDS) + per-block partial stats.
// ---------------------------------------------------------------------------
__global__ __launch_bounds__(256) void conv1_mfma(
    const unsigned short* __restrict__ act, const int* __restrict__ neigh,
    const unsigned short* __restrict__ wp, unsigned short* __restrict__ y,
    float* __restrict__ opart, int V) {
    __shared__ int shn[4 * 76];
    __shared__ float ss[64];
    __shared__ __align__(16) unsigned short est[4][16 * 32];
    const int tid = threadIdx.x;
    const int lane = tid & 63, wib = tid >> 6;
    const int v0 = (blockIdx.x * 4 + wib) * 4;
    const int m = lane & 15, quad = lane >> 4;
    int* sn = shn + wib * 76;
    {
        const int lim = V * 19 - 1;
        for (int t = lane; t < 76; t += 64) {
            int src = v0 * 19 + t;
            sn[t] = neigh[src < lim ? src : lim];
        }
    }
    for (int t = tid; t < 64; t += 256) ss[t] = 0.f;
    __syncthreads();

    const unsigned short* wl = wp + (size_t)lane * 8;
    const int b = m & 3, vq = m >> 2;

    f32x4 acc[2] = {(f32x4){0.f, 0.f, 0.f, 0.f}, (f32x4){0.f, 0.f, 0.f, 0.f}};
    union { unsigned u[4]; bf16x8 v; } w[3];
    bf16x8 bfr[3][2];
#pragma unroll
    for (int ch = 0; ch < 3; ++ch) {
        int k0 = (ch * 32 + quad * 8) >> 2;
        int k0c = k0 < 18 ? k0 : 18;
        int k1c = k0 + 1 < 18 ? k0 + 1 : 18;
        const unsigned* p0 = (const unsigned*)(act + ((size_t)sn[vq * 19 + k0c] * 4 + b) * 4);
        const unsigned* p1 = (const unsigned*)(act + ((size_t)sn[vq * 19 + k1c] * 4 + b) * 4);
        w[ch].u[0] = p0[0]; w[ch].u[1] = p0[1];
        w[ch].u[2] = p1[0]; w[ch].u[3] = p1[1];   // OOB k: weights zero-padded
#pragma unroll
        for (int t = 0; t < 2; ++t)
            bfr[ch][t] = *(const bf16x8*)(wl + (size_t)ch * 1024 + (size_t)t * 512);
    }
    __builtin_amdgcn_sched_barrier(0);
#pragma unroll
    for (int ch = 0; ch < 3; ++ch)
#pragma unroll
        for (int t = 0; t < 2; ++t)
            acc[t] = __builtin_amdgcn_mfma_f32_16x16x32_bf16(w[ch].v, bfr[ch][t], acc[t], 0, 0, 0);

    // C/D: vertex v0+quad, batch r
    float sl[2] = {0.f, 0.f}, ql[2] = {0.f, 0.f};
    unsigned short* es = est[wib];
    const bool valid = (v0 + quad < V);
#pragma unroll
    for (int r = 0; r < 4; ++r) {
#pragma unroll
        for (int t = 0; t < 2; ++t) {
            float val = acc[t][r];
            es[(quad * 4 + r) * 32 + t * 16 + m] = f2b(val);
            if (valid) { sl[t] += val; ql[t] = fmaf(val, val, ql[t]); }
        }
    }
#pragma unroll
    for (int t = 0; t < 2; ++t) {
        atomicAdd(&ss[t * 16 + m], sl[t]);
        atomicAdd(&ss[32 + t * 16 + m], ql[t]);
    }
    __syncthreads();
    {
        const int seg = lane >> 2, sub = lane & 3;   // seg = vl*4 + b
        const int vl = seg >> 2, bs = seg & 3;
        const int v = v0 + vl;
        if (v < V)
            *(uint4*)(y + ((size_t)v * 4 + bs) * 32 + sub * 8) =
                *(const uint4*)(es + seg * 32 + sub * 8);
    }
    float* pb = opart + (size_t)blockIdx.x * 64;
    for (int t = tid; t < 64; t += 256) pb[t] = ss[t];
}

// ---------------------------------------------------------------------------
// Split-K conv (levels 3-4): 8v x 2b tiles, per-SPLIT OUTPUT BUFFERS (no
// atomics, no zeroing). Coalesced fp32 stores via wave-private LDS.
// ---------------------------------------------------------------------------
template <int CIN, int COUT, int CPS, int SPLIT>
__global__ __launch_bounds__(256, 4) void conv_split(
    const unsigned short* __restrict__ act, const int* __restrict__ neigh,
    const unsigned short* __restrict__ wp, float* __restrict__ yout,
    int V, int perx, int sstr) {
    constexpr int LOGC = (CIN == 64) ? 6 : (CIN == 128) ? 7 : 8;
    constexpr int NG = 4;
    constexpr int NT = COUT / 16;
    constexpr int NGRP = NT / NG;
    constexpr int GP = 2;
    constexpr int NGR = (CPS + GP - 1) / GP;
    __shared__ int shn[4 * 152];
    __shared__ __align__(16) float est[4][16 * 64];
    const int T8 = (V + 7) >> 3;
    const int ST = (T8 + 3) >> 2;
    const int L = ST * NGRP * SPLIT;
    const int xcd = blockIdx.x & 7;
    const int p = xcd >> 2;
    const int li = (xcd & 3) * perx + (blockIdx.x >> 3);
    const int tid = threadIdx.x;
    if (li >= L) return;
    const int sp = li % SPLIT;
    const int t1 = li / SPLIT;
    const int ng = t1 % NGRP;
    const int stile = t1 / NGRP;
    const int lane = tid & 63, wib = tid >> 6;
    const int v0 = (stile * 4 + wib) * 8;
    const int m = lane & 15, quad = lane >> 4;
    const int vi = m >> 1, bb = m & 1;
    int* sn = shn + wib * 152;
    {
        const int lim = V * 19 - 1;
        for (int t = lane; t < 152; t += 64) {
            int src = v0 * 19 + t;
            sn[t] = neigh[src < lim ? src : lim];
        }
    }
    __syncthreads();

    const unsigned short* wl = wp + ((size_t)(ng * NG) * 64 + lane) * 8;
    const int c0 = sp * CPS;
    const int boff = p * 2 + bb;

    f32x4 acc[NG];
#pragma unroll
    for (int t = 0; t < NG; ++t) acc[t] = (f32x4){0.f, 0.f, 0.f, 0.f};

#pragma unroll
    for (int gi = 0; gi < NGR; ++gi) {
        bf16x8 A[GP];
        bf16x8 Bf[GP][NG];
#pragma unroll
        for (int g = 0; g < GP; ++g) {
            const int chl = gi * GP + g;
            if (chl < CPS) {
                const int ch = c0 + chl;
                int k_nb = (ch * 32) >> LOGC;
                k_nb = k_nb < 18 ? k_nb : 18;
                const int ci = ((ch * 32) & (CIN - 1)) + quad * 8;
                const int n = sn[vi * 19 + k_nb];
                A[g] = *(const bf16x8*)(act + ((size_t)n * 4 + boff) * CIN + ci);
                const unsigned short* wc = wl + (size_t)ch * NT * 512;
#pragma unroll
                for (int t = 0; t < NG; ++t)
                    Bf[g][t] = *(const bf16x8*)(wc + (size_t)t * 512);
            }
        }
        __builtin_amdgcn_sched_barrier(0);
#pragma unroll
        for (int g = 0; g < GP; ++g) {
            if (gi * GP + g < CPS) {
#pragma unroll
                for (int t = 0; t < NG; ++t)
                    acc[t] = __builtin_amdgcn_mfma_f32_16x16x32_bf16(A[g], Bf[g][t], acc[t], 0, 0, 0);
            }
        }
    }

    float* es = est[wib];
#pragma unroll
    for (int r = 0; r < 4; ++r) {
        const int vl2 = quad * 2 + (r >> 1);
        const int seg = vl2 * 2 + (r & 1);
#pragma unroll
        for (int t = 0; t < NG; ++t)
            es[seg * 64 + t * 16 + m] = acc[t][r];
    }
    __syncthreads();
    {
        float* yb = yout + (size_t)sp * sstr;
        const int seg = lane >> 2, sub = lane & 3;
        const int vl = seg >> 1, bst = seg & 1;
        const int v = v0 + vl;
        if (v < V) {
            const float* src = es + seg * 64 + sub * 16;
            float* dst = yb + ((size_t)v * 4 + p * 2 + bst) * COUT + ng * 64 + sub * 16;
#pragma unroll
            for (int j = 0; j < 4; ++j)
                *(float4*)(dst + j * 4) = *(const float4*)(src + j * 4);
        }
    }
}

// ---------------------------------------------------------------------------
// Sum per-block partials: grid.x = 2*C; st[c] = sum_b part[b][c]
// ---------------------------------------------------------------------------
__global__ __launch_bounds__(256) void reduce_stats(const float* __restrict__ part,
                                                    float* __restrict__ st, int nblk) {
    __shared__ float red[256];
    int c = blockIdx.x;
    int C2 = gridDim.x;
    float s = 0.f;
    for (int b = threadIdx.x; b < nblk; b += 256) s += part[(size_t)b * C2 + c];
    red[threadIdx.x] = s;
    __syncthreads();
    for (int off = 128; off > 0; off >>= 1) {
        if (threadIdx.x < off) red[threadIdx.x] += red[threadIdx.x + off];
        __syncthreads();
    }
    if (threadIdx.x == 0) st[c] = red[0];
}

// ---------------------------------------------------------------------------
// Per-channel sum/sumsq over NS split buffers -> per-XCD replicated stats
// ---------------------------------------------------------------------------
template <int C, int NS>
__global__ __launch_bounds__(256) void stats_split(const float* __restrict__ y,
                                                   float* __restrict__ st,
                                                   int rows, int sstr) {
    constexpr int LOGC = (C == 128) ? 7 : 8;
    __shared__ float ss[2 * C];
    int tid = threadIdx.x;
    for (int i = tid; i < 2 * C; i += 256) ss[i] = 0.f;
    __syncthreads();
    int c = tid & (C - 1);
    const int rpb = 256 >> LOGC;
    float s = 0.f, q = 0.f;
    for (int r = blockIdx.x * rpb + (tid >> LOGC); r < rows; r += gridDim.x * rpb) {
        float v = 0.f;
#pragma unroll
        for (int k = 0; k < NS; ++k) v += y[(size_t)k * sstr + (size_t)r * C + c];
        s += v;
        q = fmaf(v, v, q);
    }
    atomicAdd(&ss[c], s);
    atomicAdd(&ss[C + c], q);
    __syncthreads();
    float* orep = st + (blockIdx.x & 7) * STREP;
    for (int i = tid; i < 2 * C; i += 256) atomicAdd(&orep[i], ss[i]);
}

// ---------------------------------------------------------------------------
// bnleaky(sum of NS splits, replicated stats) -> finished bf16
// ---------------------------------------------------------------------------
template <int C, int NS>
__global__ __launch_bounds__(256) void finalize_split(
    const float* __restrict__ yin, const float* __restrict__ st,
    const float* __restrict__ g, const float* __restrict__ be, float invN,
    unsigned short* __restrict__ out, int total4, int sstr) {
    __shared__ float la[C], lc[C];
    int tid = threadIdx.x;
    for (int c = tid; c < C; c += 256) {
        float s = 0.f, q = 0.f;
#pragma unroll
        for (int k = 0; k < 8; ++k) { s += st[k * STREP + c]; q += st[k * STREP + C + c]; }
        float mu = s * invN;
        float var = fmaf(q, invN, -mu * mu);
        float a = g[c] * rsqrtf(var + 1e-5f);
        la[c] = a;
        lc[c] = fmaf(-mu, a, be[c]);
    }
    __syncthreads();
    int idx = blockIdx.x * 256 + tid;
    if (idx >= total4) return;
    int c0 = (idx * 4) & (C - 1);
    float4 yv = make_float4(0.f, 0.f, 0.f, 0.f);
#pragma unroll
    for (int k = 0; k < NS; ++k) {
        float4 t = *(const float4*)(yin + (size_t)k * sstr + (size_t)idx * 4);
        yv.x += t.x; yv.y += t.y; yv.z += t.z; yv.w += t.w;
    }
    float o0 = leaky_f(fmaf(la[c0 + 0], yv.x, lc[c0 + 0]));
    float o1 = leaky_f(fmaf(la[c0 + 1], yv.y, lc[c0 + 1]));
    float o2 = leaky_f(fmaf(la[c0 + 2], yv.z, lc[c0 + 2]));
    float o3 = leaky_f(fmaf(la[c0 + 3], yv.w, lc[c0 + 3]));
    unsigned r0 = (unsigned)f2b(o0) | ((unsigned)f2b(o1) << 16);
    unsigned r1 = (unsigned)f2b(o2) | ((unsigned)f2b(o3) << 16);
    ((uint2*)out)[idx] = make_uint2(r0, r1);
}

// ---------------------------------------------------------------------------
// Mean-pool on [Vin][4][C] -> [VP][4][C]. BN: producer bnleaky (plain stats).
// ---------------------------------------------------------------------------
template <int C, bool BN>
__global__ __launch_bounds__(256) void pool_kernel(
    const unsigned short* __restrict__ in, const int* __restrict__ neigh,
    const float* __restrict__ pstats, const float* __restrict__ pg,
    const float* __restrict__ pe, float invN,
    unsigned short* __restrict__ out, int total) {
    constexpr int LC4 = (C == 32) ? 3 : (C == 64) ? 4 : 5;
    __shared__ float2 lac[BN ? C : 1];
    int tid = threadIdx.x;
    if constexpr (BN) {
        for (int c = tid; c < C; c += 256) {
            float s = pstats[c], q = pstats[C + c];
            float mu = s * invN;
            float var = fmaf(q, invN, -mu * mu);
            float a = pg[c] * rsqrtf(var + 1e-5f);
            lac[c] = make_float2(a, fmaf(-mu, a, pe[c]));
        }
        __syncthreads();
    }
    int idx = blockIdx.x * 256 + tid;
    if (idx >= total) return;
    int c4 = idx & ((C / 4) - 1);
    int b = (idx >> LC4) & 3;
    int vp = idx >> (LC4 + 2);
    float a0 = 0.f, a1 = 0.f, a2 = 0.f, a3 = 0.f;
    for (int k = 0; k < 19; ++k) {
        int n = neigh[vp * 19 + k];
        uint2 d = *(const uint2*)(in + ((size_t)n * 4 + b) * C + c4 * 4);
        float f0 = b2f((unsigned short)(d.x & 0xffff));
        float f1 = b2f((unsigned short)(d.x >> 16));
        float f2 = b2f((unsigned short)(d.y & 0xffff));
        float f3 = b2f((unsigned short)(d.y >> 16));
        if constexpr (BN) {
            float2 t0 = lac[c4 * 4 + 0], t1 = lac[c4 * 4 + 1];
            float2 t2 = lac[c4 * 4 + 2], t3 = lac[c4 * 4 + 3];
            f0 = leaky_f(fmaf(f0, t0.x, t0.y));
            f1 = leaky_f(fmaf(f1, t1.x, t1.y));
            f2 = leaky_f(fmaf(f2, t2.x, t2.y));
            f3 = leaky_f(fmaf(f3, t3.x, t3.y));
        }
        a0 += f0; a1 += f1; a2 += f2; a3 += f3;
    }
    const float r = 1.f / 19.f;
    unsigned r0 = (unsigned)f2b(a0 * r) | ((unsigned)f2b(a1 * r) << 16);
    unsigned r1 = (unsigned)f2b(a2 * r) | ((unsigned)f2b(a3 * r) << 16);
    ((uint2*)out)[idx] = make_uint2(r0, r1);
}

// ---------------------------------------------------------------------------
// FC over bnleaky(sum of 8 splits of y4_2 [642][4][256]); per-block partials
// ---------------------------------------------------------------------------
__global__ __launch_bounds__(256) void fc_partial(
    const float* __restrict__ y, const float* __restrict__ wfc,
    const float* __restrict__ st, const float* __restrict__ g,
    const float* __restrict__ be, float invN, float* __restrict__ fcpart,
    int sstr) {
    __shared__ float la[256], lc[256];
    __shared__ float sh[4];
    int tid = threadIdx.x;
    if (tid < 4) sh[tid] = 0.f;
    {
        int c = tid;
        float s = 0.f, q = 0.f;
#pragma unroll
        for (int k = 0; k < 8; ++k) { s += st[k * STREP + c]; q += st[k * STREP + 256 + c]; }
        float mu = s * invN;
        float var = fmaf(q, invN, -mu * mu);
        float a = g[c] * rsqrtf(var + 1e-5f);
        la[c] = a;
        lc[c] = fmaf(-mu, a, be[c]);
    }
    __syncthreads();
    float p0 = 0.f, p1 = 0.f, p2 = 0.f, p3 = 0.f;
    const int VC = 642 * 256;
    for (int idx = blockIdx.x * 256 + tid; idx < VC; idx += gridDim.x * 256) {
        int c = idx & 255;
        float a = la[c], cc = lc[c];
        float w = wfc[idx];
        size_t base = ((size_t)(idx >> 8) << 10) + c;   // v*1024 + c
        float y0 = 0.f, y1 = 0.f, y2 = 0.f, y3 = 0.f;
#pragma unroll
        for (int k = 0; k < 8; ++k) {
            const float* yk = y + (size_t)k * sstr;
            y0 += yk[base];
            y1 += yk[base + 256];
            y2 += yk[base + 512];
            y3 += yk[base + 768];
        }
        p0 = fmaf(w, leaky_f(fmaf(a, y0, cc)), p0);
        p1 = fmaf(w, leaky_f(fmaf(a, y1, cc)), p1);
        p2 = fmaf(w, leaky_f(fmaf(a, y2, cc)), p2);
        p3 = fmaf(w, leaky_f(fmaf(a, y3, cc)), p3);
    }
    atomicAdd(&sh[0], p0);
    atomicAdd(&sh[1], p1);
    atomicAdd(&sh[2], p2);
    atomicAdd(&sh[3], p3);
    __syncthreads();
    if (tid < 4) fcpart[blockIdx.x * 4 + tid] = sh[tid];
}

__global__ void fc_finalize(const float* __restrict__ fcpart, const float* __restrict__ m,
                            const float* __restrict__ wm, const float* __restrict__ bm,
                            const float* __restrict__ wfc, const float* __restrict__ bfc,
                            float* __restrict__ out, int nblk) {
    int b = threadIdx.x;
    if (b < 4) {
        float acc = 0.f;
        for (int i = 0; i < nblk; ++i) acc += fcpart[i * 4 + b];
        float mv = m[b];
        float s = 0.f;
#pragma unroll
        for (int j = 0; j < 4; ++j) {
            float mm = fmaxf(fmaf(mv, wm[j], bm[j]), 0.f);
            s = fmaf(mm, wfc[642 * 256 + j], s);
        }
        out[b] = acc + s + bfc[0];
    }
}

extern "C" void kernel_launch(void* const* d_in, const int* in_sizes, int n_in,
                              void* d_out, int out_size, void* d_ws, size_t ws_size,
                              hipStream_t stream) {
    const float* x = (const float*)d_in[0];
    const float* m = (const float*)d_in[1];
    const int* n0 = (const int*)d_in[2];
    const int* n1 = (const int*)d_in[3];
    const int* n2 = (const int*)d_in[4];
    const int* n3 = (const int*)d_in[5];

    // conv biases cancel exactly through batch-stats BN -> omitted.
    const float* G[8]  = {(const float*)d_in[8],  (const float*)d_in[12],
                          (const float*)d_in[16], (const float*)d_in[20],
                          (const float*)d_in[24], (const float*)d_in[28],
                          (const float*)d_in[32], (const float*)d_in[36]};
    const float* E[8]  = {(const float*)d_in[9],  (const float*)d_in[13],
                          (const float*)d_in[17], (const float*)d_in[21],
                          (const float*)d_in[25], (const float*)d_in[29],
                          (const float*)d_in[33], (const float*)d_in[37]};
    const float* wm  = (const float*)d_in[38];
    const float* bm  = (const float*)d_in[39];
    const float* wfc = (const float*)d_in[40];
    const float* bfc = (const float*)d_in[41];

    char* wsb = (char*)d_ws;
    unsigned short* X0  = (unsigned short*)(wsb + 0 * MB);
    unsigned short* Y1  = (unsigned short*)(wsb + 2 * MB);   // raw conv1_1
    unsigned short* Y2  = (unsigned short*)(wsb + 13 * MB);  // raw conv1_2
    unsigned short* P1  = (unsigned short*)(wsb + 24 * MB);  // finished pool1
    unsigned short* Y21 = (unsigned short*)(wsb + 27 * MB);  // raw conv2_1
    unsigned short* Y22 = (unsigned short*)(wsb + 33 * MB);  // raw conv2_2
    unsigned short* P2  = (unsigned short*)(wsb + 39 * MB);  // finished pool2
    unsigned short* WP  = (unsigned short*)(wsb + 41 * MB);
    float* part = (float*)(wsb + 47 * MB);
    float* Z    = (float*)(wsb + 49 * MB);                   // split buffers (21 MB, reused)
    unsigned short* F31 = (unsigned short*)(wsb + 70 * MB);
    unsigned short* F32 = (unsigned short*)(wsb + 73 * MB);
    unsigned short* P3  = (unsigned short*)(wsb + 76 * MB);
    unsigned short* F41 = (unsigned short*)(wsb + 77 * MB);
    float* st    = (float*)(wsb + 79 * MB);                  // 8 x 4096 floats (zeroed)
    float* fcpart = (float*)(wsb + 79 * MB + 131072);

    static const int wp_off[8] = {0, 3072, 22528, 61440, 139264, 303104, 614400, 1269760};
    const int SSTR3 = 2562 * 4 * 128;   // 1,311,744 floats per split
    const int SSTR4 = 642 * 4 * 256;    //   657,408 floats per split

    const float iN1 = 1.f / (40962.f * 4.f);
    const float iN2 = 1.f / (10242.f * 4.f);
    const float iN3 = 1.f / (2562.f * 4.f);
    const float iN4 = 1.f / (642.f * 4.f);

    hipMemsetAsync(st, 0, 131072, stream);
    cast_x<<<2561, 256, 0, stream>>>(x, X0, 40962 * 16);
    prepack_all<<<9824, 256, 0, stream>>>((const float*)d_in[6], (const float*)d_in[10],
                                          (const float*)d_in[14], (const float*)d_in[18],
                                          (const float*)d_in[22], (const float*)d_in[26],
                                          (const float*)d_in[30], (const float*)d_in[34], WP);

    // ---- Level 1 (V=40962) ----
    conv1_mfma<<<2561, 256, 0, stream>>>(X0, n0, WP + wp_off[0], Y1, part, 40962);
    reduce_stats<<<64, 256, 0, stream>>>(part, st + 0 * 4096, 2561);
    // conv1_2: T16=2561, ST=641, perx=161, grid=1288; BN(st0) at gather
    conv_fuse<32, 2, 19, true><<<1288, 256, 0, stream>>>(
        Y1, n0, WP + wp_off[1], Y2, part, st + 0 * 4096, G[0], E[0], iN1, 40962, 161);
    reduce_stats<<<64, 256, 0, stream>>>(part, st + 1 * 4096, 1288);
    pool_kernel<32, true><<<1281, 256, 0, stream>>>(Y2, n0, st + 1 * 4096, G[1], E[1], iN1,
                                                    P1, 10242 * 4 * 8);

    // ---- Level 2 (V=10242) ----  T16=641, ST=161, perx=41, grid=328
    conv_fuse<32, 4, 19, false><<<328, 256, 0, stream>>>(
        P1, n1, WP + wp_off[2], Y21, part, nullptr, nullptr, nullptr, 0.f, 10242, 41);
    reduce_stats<<<128, 256, 0, stream>>>(part, st + 2 * 4096, 328);
    conv_fuse<64, 4, 38, true><<<328, 256, 0, stream>>>(
        Y21, n1, WP + wp_off[3], Y22, part, st + 2 * 4096, G[2], E[2], iN2, 10242, 41);
    reduce_stats<<<128, 256, 0, stream>>>(part, st + 3 * 4096, 328);
    pool_kernel<64, true><<<641, 256, 0, stream>>>(Y22, n1, st + 3 * 4096, G[3], E[3], iN2,
                                                   P2, 2562 * 4 * 16);

    // ---- Level 3 (V=2562) ----  T8=321, ST8=81, NGRP=2, SPLIT=4 -> L=648, perx=162, grid=1296
    conv_split<64, 128, 10, 4><<<1296, 256, 0, stream>>>(
        P2, n2, WP + wp_off[4], Z, 2562, 162, SSTR3);
    stats_split<128, 4><<<480, 256, 0, stream>>>(Z, st + 4 * 4096, 10248, SSTR3);
    finalize_split<128, 4><<<1281, 256, 0, stream>>>(Z, st + 4 * 4096, G[4], E[4], iN3,
                                                     F31, 327936, SSTR3);
    conv_split<128, 128, 19, 4><<<1296, 256, 0, stream>>>(
        F31, n2, WP + wp_off[5], Z, 2562, 162, SSTR3);
    stats_split<128, 4><<<480, 256, 0, stream>>>(Z, st + 5 * 4096, 10248, SSTR3);
    finalize_split<128, 4><<<1281, 256, 0, stream>>>(Z, st + 5 * 4096, G[5], E[5], iN3,
                                                     F32, 327936, SSTR3);
    pool_kernel<128, false><<<321, 256, 0, stream>>>(F32, n2, nullptr, nullptr, nullptr, 0.f,
                                                     P3, 642 * 4 * 32);

    // ---- Level 4 (V=642) ----  T8=81, ST8=21, NGRP=4, SPLIT=8 -> L=672, perx=168, grid=1344
    conv_split<128, 256, 10, 8><<<1344, 256, 0, stream>>>(
        P3, n3, WP + wp_off[6], Z, 642, 168, SSTR4);
    stats_split<256, 8><<<480, 256, 0, stream>>>(Z, st + 6 * 4096, 2568, SSTR4);
    finalize_split<256, 8><<<642, 256, 0, stream>>>(Z, st + 6 * 4096, G[6], E[6], iN4,
                                                    F41, 164352, SSTR4);
    conv_split<256, 256, 19, 8><<<1344, 256, 0, stream>>>(
        F41, n3, WP + wp_off[7], Z, 642, 168, SSTR4);
    stats_split<256, 8><<<480, 256, 0, stream>>>(Z, st + 7 * 4096, 2568, SSTR4);

    // ---- FC ----
    fc_partial<<<128, 256, 0, stream>>>(Z, wfc, st + 7 * 4096, G[7], E[7], iN4, fcpart, SSTR4);
    fc_finalize<<<1, 64, 0, stream>>>(fcpart, m, wm, bm, wfc, bfc, (float*)d_out, 128);
}